// Round 1
// baseline (233.387 us; speedup 1.0000x reference)
//
#include <hip/hip_runtime.h>

// NMS3D: x (4,2,64,256,256) f32, 3x3x3 neighborhood-max excluding center,
// edge padding == index clamping.
//
// R5: cooperative LDS staging. Block = (64,8) covers 8 rows x W=256 x DC=8
// depth slices. Per z-slice the block stages only the 10 UNIQUE rows it
// needs (vs 24 row-loads under the old 3-rows-per-wave scheme) via
// global_load_lds (async, no VGPR round-trip). 3-buffer rotation with raw
// s_barrier + counted vmcnt (stage loads for slice t+1 stay in flight
// across the barrier; no in-loop vmcnt(0) drain). The z-rolling
// vmax9/cross8 register state is unchanged (proven correct); the 9xfloat4
// global pipeline is gone -> lower VGPR -> launch_bounds(512,6) = 24
// waves/CU (was 16).

constexpr int D_   = 64;
constexpr int H_   = 256;
constexpr int W_   = 256;
constexpr int HW_  = H_ * W_;
constexpr int NVOL = 8;     // B * CH
constexpr int DC   = 8;     // depth slices emitted per block
constexpr int RY   = 8;     // output rows per block
constexpr int RS   = RY + 2;    // rows staged per slice
constexpr int NBUF = 3;     // LDS slice buffers (1-barrier rotation)
constexpr int S    = DC + 2;    // slices touched: z0-1 .. z0+DC

__device__ __forceinline__ float f3(float a, float b, float c) {
    return fmaxf(fmaxf(a, b), c);
}

// async global->LDS, 16B per lane; LDS dest = wave-uniform base + lane*16
__device__ __forceinline__ void gload16(const float* g, float* l) {
    __builtin_amdgcn_global_load_lds(
        (const __attribute__((address_space(1))) void*)g,
        (__attribute__((address_space(3))) void*)l,
        16, 0, 0);
}

__global__ __launch_bounds__(512, 6)
void nms3d(const float* __restrict__ x, float* __restrict__ out)
{
    __shared__ float lds[NBUF][RS * W_];   // 3 x 10KiB = 30 KiB

    const int tx = threadIdx.x;            // 0..63 = lane id (wave = one row)
    const int ty = threadIdx.y;            // 0..7  = wave id
    const int h0 = blockIdx.y * RY;
    const int h  = h0 + ty;                // this wave's output row
    const int n  = blockIdx.z;
    const int z0 = blockIdx.x * DC;
    const int c  = tx << 2;

    const float* __restrict__ base  = x   + (size_t)n * D_ * HW_;
    float* __restrict__       obase = out + (size_t)n * D_ * HW_;

    // staging assignment: wave ty stages LDS row ty = global row clamp(h0-1+ty);
    // waves 0,1 additionally stage LDS rows 8,9.
    const int grA = min(max(h0 - 1 + ty, 0), H_ - 1);
    const int grB = min(max(h0 - 1 + RY + ty, 0), H_ - 1);
    const float* gA = base + (size_t)grA * W_ + c;
    const float* gB = base + (size_t)grB * W_ + c;

    // stage slice index t (z = clamp(z0-1+t)) into lds[t % NBUF]
    auto stage = [&](int t) {
        const int zc = min(max(z0 - 1 + t, 0), D_ - 1);
        const size_t zo = (size_t)zc * HW_;
        float* lp = &lds[t % NBUF][0];
        gload16(gA + zo, lp + ty * W_);
        if (ty < 2) gload16(gB + zo, lp + (RY + ty) * W_);
    };

    stage(0);   // prologue: slice z0-1 in flight

    // rolling depth state
    float4 vm9_pp = {0,0,0,0};  // vmax9[z-2]
    float4 vm9_p  = {0,0,0,0};  // vmax9[z-1]
    float4 cr8_p  = {0,0,0,0};  // cross8[z-1]
    float4 vprev  = {0,0,0,0};  // v[z-1]

#pragma unroll
    for (int t = 0; t < S; ++t) {
        if (t + 1 < S) {
            stage(t + 1);   // keep next slice's loads in flight across the barrier
            // wait only for slice-t loads (the k just-issued stay outstanding);
            // any older store drains too -- harmless.
            if (ty < 2) asm volatile("s_waitcnt vmcnt(2)" ::: "memory");
            else        asm volatile("s_waitcnt vmcnt(1)" ::: "memory");
        } else {
            asm volatile("s_waitcnt vmcnt(0)" ::: "memory");   // final drain (once)
        }
        __builtin_amdgcn_s_barrier();          // raw barrier: no implicit vmcnt(0)
        asm volatile("" ::: "memory");         // keep ds_reads below the barrier

        // slice zi = z0-1+t, rows h-1,h,h+1 from LDS (conflict-free b128 reads)
        const float* p = &lds[t % NBUF][0];
        const float4 a0 = *(const float4*)(p + (ty    ) * W_ + c);
        const float4 b0 = *(const float4*)(p + (ty + 1) * W_ + c);
        const float4 d0 = *(const float4*)(p + (ty + 2) * W_ + c);

        float4 va;
        va.x = fmaxf(a0.x, d0.x); va.y = fmaxf(a0.y, d0.y);
        va.z = fmaxf(a0.z, d0.z); va.w = fmaxf(a0.w, d0.w);

        float vaL = __shfl_up(va.w, 1);   if (tx == 0)  vaL = va.x;
        float vaR = __shfl_down(va.x, 1); if (tx == 63) vaR = va.w;
        float bL  = __shfl_up(b0.w, 1);   if (tx == 0)  bL  = b0.x;
        float bR  = __shfl_down(b0.x, 1); if (tx == 63) bR  = b0.w;

        float4 hv, nb;
        hv.x = f3(vaL, va.x, va.y);  hv.y = f3(va.x, va.y, va.z);
        hv.z = f3(va.y, va.z, va.w); hv.w = f3(va.z, va.w, vaR);
        nb.x = fmaxf(bL,  b0.y);  nb.y = fmaxf(b0.x, b0.z);
        nb.z = fmaxf(b0.y, b0.w); nb.w = fmaxf(b0.z, bR);

        float4 c8, cur;                      // cross8[zi], vmax9[zi]
        c8.x  = fmaxf(hv.x, nb.x); c8.y  = fmaxf(hv.y, nb.y);
        c8.z  = fmaxf(hv.z, nb.z); c8.w  = fmaxf(hv.w, nb.w);
        cur.x = fmaxf(c8.x, b0.x); cur.y = fmaxf(c8.y, b0.y);
        cur.z = fmaxf(c8.z, b0.z); cur.w = fmaxf(c8.w, b0.w);

        if (t >= 2) {
            // emit out[zi-1]: max_nc = max(vmax9[zi-2], cross8[zi-1], vmax9[zi])
            const int zi = z0 - 1 + t;
            float4 mx, o;
            mx.x = f3(vm9_pp.x, cr8_p.x, cur.x);
            mx.y = f3(vm9_pp.y, cr8_p.y, cur.y);
            mx.z = f3(vm9_pp.z, cr8_p.z, cur.z);
            mx.w = f3(vm9_pp.w, cr8_p.w, cur.w);
            o.x = vprev.x > mx.x ? vprev.x : 0.0f;
            o.y = vprev.y > mx.y ? vprev.y : 0.0f;
            o.z = vprev.z > mx.z ? vprev.z : 0.0f;
            o.w = vprev.w > mx.w ? vprev.w : 0.0f;
            *(float4*)(obase + (size_t)(zi - 1) * HW_ + (size_t)h * W_ + c) = o;
        }
        vm9_pp = vm9_p; vm9_p = cur; cr8_p = c8; vprev = b0;
    }
}

extern "C" void kernel_launch(void* const* d_in, const int* in_sizes, int n_in,
                              void* d_out, int out_size, void* d_ws, size_t ws_size,
                              hipStream_t stream)
{
    const float* x = (const float*)d_in[0];
    float* out = (float*)d_out;
    dim3 block(64, RY, 1);                    // 512 threads = 8 waves
    dim3 grid(D_ / DC, H_ / RY, NVOL);        // 8 x 32 x 8 = 2048 blocks
    nms3d<<<grid, block, 0, stream>>>(x, out);
}